// Round 6
// baseline (603.674 us; speedup 1.0000x reference)
//
#include <hip/hip_runtime.h>
#include <stdint.h>

typedef __attribute__((ext_vector_type(8))) _Float16 f16x8;
typedef __attribute__((ext_vector_type(4))) float f32x4;

#define N_NODES 4096
#define N_EDGES 32768

__device__ __forceinline__ float sigm(float x) { return 1.f / (1.f + __expf(-x)); }

// pack 8 consecutive f32 -> f16x8 (RNE)
__device__ __forceinline__ f16x8 packh8(const float* p) {
  f16x8 r;
#pragma unroll
  for (int i = 0; i < 8; ++i) r[i] = (_Float16)p[i];
  return r;
}

// ---------------------------------------------------------------------------
// prep (merged): blocks 0..127  -> WnnT[n][k] fp16 from Wnn[k][n] f32
//                blocks 128..319 -> We1T / We2T fp16 transposes
// ---------------------------------------------------------------------------
__global__ void prep_all(const float* __restrict__ Wnn,
                         const float* __restrict__ We1,
                         const float* __restrict__ We2,
                         _Float16* __restrict__ WnnT,
                         _Float16* __restrict__ We1T,
                         _Float16* __restrict__ We2T) {
  __shared__ float tile[128][33];
  const int b = blockIdx.x, t = threadIdx.x;
  if (b < 128) {
    const int nb = b * 32;
    for (int i = 0; i < 16; ++i) {
      int g = i * 256 + t;          // 4096 = 128k x 32n
      int k = g >> 5, j = g & 31;
      tile[k][j] = Wnn[(size_t)k * 4096 + nb + j];
    }
    __syncthreads();
    for (int i = 0; i < 16; ++i) {
      int g = i * 256 + t;
      int j = g >> 7, k = g & 127;
      WnnT[(size_t)(nb + j) * 128 + k] = (_Float16)tile[k][j];
    }
  } else {
    int idx = (b - 128) * 256 + t;   // < 49152
    if (idx < 32768) {
      int n = idx >> 8, k = idx & 255;
      We1T[idx] = (_Float16)We1[(size_t)k * 128 + n];
    } else {
      int j = idx - 32768;
      int n = j >> 7, k = j & 127;
      We2T[j] = (_Float16)We2[(size_t)k * 128 + n];
    }
  }
}

// ---------------------------------------------------------------------------
// CSR build (once per launch; edge_index is launch-constant)
// ---------------------------------------------------------------------------
__global__ void csr_zero(int* __restrict__ rowcnt) {
  rowcnt[blockIdx.x * 256 + threadIdx.x] = 0;
}
__global__ void csr_count(const int* __restrict__ eidx, int* __restrict__ rowcnt) {
  int e = blockIdx.x * 256 + threadIdx.x;
  atomicAdd(&rowcnt[eidx[N_EDGES + e]], 1);
}
__global__ void csr_scan(const int* __restrict__ rowcnt,
                         int* __restrict__ rowptr, int* __restrict__ cursor) {
  __shared__ int part[1024];
  const int t = threadIdx.x;
  const int base = t * 4;
  int s0 = rowcnt[base], s1 = rowcnt[base + 1], s2 = rowcnt[base + 2], s3 = rowcnt[base + 3];
  int sum = s0 + s1 + s2 + s3;
  part[t] = sum;
  __syncthreads();
  for (int off = 1; off < 1024; off <<= 1) {
    int v = (t >= off) ? part[t - off] : 0;
    __syncthreads();
    part[t] += v;
    __syncthreads();
  }
  int excl = part[t] - sum;
  int p0 = excl, p1 = excl + s0, p2 = excl + s0 + s1, p3 = excl + s0 + s1 + s2;
  rowptr[base] = p0; rowptr[base + 1] = p1; rowptr[base + 2] = p2; rowptr[base + 3] = p3;
  cursor[base] = p0; cursor[base + 1] = p1; cursor[base + 2] = p2; cursor[base + 3] = p3;
  if (t == 0) rowptr[4096] = N_EDGES;
}
__global__ void csr_fill(const int* __restrict__ eidx, int* __restrict__ cursor,
                         int* __restrict__ eids) {
  int e = blockIdx.x * 256 + threadIdx.x;
  int slot = atomicAdd(&cursor[eidx[N_EDGES + e]], 1);
  eids[slot] = e;
}

// ---------------------------------------------------------------------------
// proj_node: h = relu(node_feats @ W_p + b_p) -> hid f32 (in d_out)
// ---------------------------------------------------------------------------
__global__ void proj_node_f(const float* __restrict__ nf,
                            const float* __restrict__ Wp,
                            const float* __restrict__ bp,
                            float* __restrict__ h) {
  int idx = blockIdx.x * 256 + threadIdx.x;
  int n = idx >> 6, c = idx & 63;
  float acc = bp[c];
  for (int k = 0; k < 64; ++k)
    acc = fmaf(nf[n * 64 + k], Wp[k * 64 + c], acc);
  h[idx] = fmaxf(acc, 0.f);
}

// ---------------------------------------------------------------------------
// proj_edge: e = relu(edge_attr @ W_pe + b_pe); Wpe cached in LDS; 32 e/block.
// ---------------------------------------------------------------------------
__launch_bounds__(256)
__global__ void proj_edge_f2(const float* __restrict__ ea,
                             const float* __restrict__ Wpe,
                             const float* __restrict__ bpe,
                             float* __restrict__ e) {
  __shared__ float sw[16 * 128];
  __shared__ float sb[128];
  __shared__ float sa[32][17];
  const int t = threadIdx.x;
  const int ebase = blockIdx.x * 32;
  for (int g = t; g < 2048; g += 256) sw[g] = Wpe[g];
  if (t < 128) sb[t] = bpe[t];
  for (int g = t; g < 512; g += 256) {
    int r = g >> 4, k = g & 15;
    sa[r][k] = ea[(size_t)(ebase + r) * 16 + k];
  }
  __syncthreads();
  int c = t & 127, eg = t >> 7;
  float wc[16];
#pragma unroll
  for (int k = 0; k < 16; ++k) wc[k] = sw[k * 128 + c];
  float bv = sb[c];
#pragma unroll
  for (int i = 0; i < 16; ++i) {
    int ee = eg * 16 + i;
    float acc = bv;
#pragma unroll
    for (int k = 0; k < 16; ++k) acc = fmaf(sa[ee][k], wc[k], acc);
    e[(size_t)(ebase + ee) * 128 + c] = fmaxf(acc, 0.f);
  }
}

// ---------------------------------------------------------------------------
// fused_msg (MFMA fp16 v14): 512 blocks x 256 threads (4 waves), 64 e/block.
// R17 post-mortem: v13 (4-wave, msg[8][4]) hit the 256-VGPR cap exactly and
// spilled (WRITE 18MB). VGPR model confirmed: 512 VGPR/SIMD pool; waves/SIMD
// = 512/alloc; cap = 512 / (2nd launch_bounds arg... effectively). The
// pipeline needs ~200 VGPR -> 4-wave block AND v8's per-wave workload.
// v14: per-wave work IDENTICAL to v8 (4 e-subtiles, msg[4][4]) but 4 waves /
// 64 edges / block, 512 blocks. bb0+bb1(128)+msg(16)+C(16)+misc ~ 200 VGPR
// < 256 cap -> double-buffer unspilled; ~200 VGPR -> 2 waves/SIMD and 2
// blocks/CU (LDS 33.4KB) -> same 8 waves/CU as v8 + B-latency hiding +
// decoupled block barriers. Clean latency-theory test, spill eliminated.
// Kept: per-wave dg rotation, opaque A-LDS offset, bnn in MFMA C-init,
// XOR-swizzled Ae.
// ---------------------------------------------------------------------------
__device__ __forceinline__ void loadB(f16x8 (&BB)[4][4], float (&BN)[4],
                                      const _Float16* __restrict__ wb,
                                      const float* __restrict__ bnn,
                                      int dgr, int fcol) {
#pragma unroll
  for (int c = 0; c < 4; ++c) {
    const _Float16* p = wb + (size_t)(dgr * 4 + c) * 8192;
#pragma unroll
    for (int kk = 0; kk < 4; ++kk) BB[c][kk] = *(const f16x8*)(p + kk * 32);
    BN[c] = bnn[(dgr * 4 + c) * 64 + fcol];
  }
}

__device__ __forceinline__ void computeB4(const f16x8 (&BB)[4][4], const float (&BN)[4],
                                          const _Float16* __restrict__ Ae,
                                          const float* __restrict__ Hs,
                                          float (&msg)[4][4],
                                          int dgr, int l15, int q, int aoff) {
#pragma unroll
  for (int m = 0; m < 4; ++m) {
    const int arow = (m * 16 + l15) * 128 + aoff;
    f32x4 C[4];
#pragma unroll
    for (int c = 0; c < 4; ++c)
      C[c] = (f32x4){BN[c], BN[c], BN[c], BN[c]};   // bias pre-loaded
#pragma unroll
    for (int kk = 0; kk < 4; ++kk) {
      int kgp = (kk * 4 + q) ^ l15;   // e&15 == l15 for A rows
      f16x8 a = *(const f16x8*)&Ae[arow + kgp * 8];
#pragma unroll
      for (int c = 0; c < 4; ++c)
        C[c] = __builtin_amdgcn_mfma_f32_16x16x32_f16(a, BB[c][kk], C[c], 0, 0, 0);
    }
#pragma unroll
    for (int c = 0; c < 4; ++c) {
      int d = dgr * 4 + c;
      float4 hv = *(const float4*)&Hs[d * 68 + m * 16 + q * 4];
      msg[m][0] = fmaf(hv.x, fmaxf(C[c][0], 0.f), msg[m][0]);
      msg[m][1] = fmaf(hv.y, fmaxf(C[c][1], 0.f), msg[m][1]);
      msg[m][2] = fmaf(hv.z, fmaxf(C[c][2], 0.f), msg[m][2]);
      msg[m][3] = fmaf(hv.w, fmaxf(C[c][3], 0.f), msg[m][3]);
    }
  }
}

__launch_bounds__(256, 2)
__global__ void fused_msg_m(const float* __restrict__ ebf,
                            const float* __restrict__ hid,
                            const _Float16* __restrict__ WnnT,
                            const float* __restrict__ bnn,
                            const int* __restrict__ eidx,
                            _Float16* __restrict__ msgbuf) {
  __shared__ __align__(16) _Float16 Ae[64 * 128];  // 16,384 B, XOR-swizzled
  __shared__ __align__(16) float Hs[64 * 68];      // 17,408 B  Hs[d*68+e]
  const int t = threadIdx.x;       // 0..255
  const int w = t >> 6, l = t & 63, l15 = l & 15, q = l >> 4;
  const int fw = w;                // f cols: fw*16 + l15 (4 waves = 4 f-groups)
  const int ebase = blockIdx.x * 64;
  const int rot = (blockIdx.x * 4 + w) & 15;   // per-WAVE rotation

  // stage Hs (transposed): 64 e x 16 d-quads
#pragma unroll
  for (int i = 0; i < 4; ++i) {
    int g = i * 256 + t;           // 1024 = 64 e x 16 d4
    int e = g >> 4, d4 = g & 15;
    int r = eidx[ebase + e];
    float4 v = *(const float4*)&hid[(size_t)r * 64 + d4 * 4];
    Hs[(d4 * 4 + 0) * 68 + e] = v.x;
    Hs[(d4 * 4 + 1) * 68 + e] = v.y;
    Hs[(d4 * 4 + 2) * 68 + e] = v.z;
    Hs[(d4 * 4 + 3) * 68 + e] = v.w;
  }
  // stage Ae: 64 edges x 128 k, f32 -> fp16 once, XOR-swizzled 16B blocks
#pragma unroll
  for (int i = 0; i < 4; ++i) {
    int g = i * 256 + t;           // 1024 = 64 e x 16 groups of 8 halves
    int e = g >> 4, kg = g & 15;
    f16x8 v = packh8(&ebf[(size_t)(ebase + e) * 128 + kg * 8]);
    int kgp = kg ^ (e & 15);
    *(f16x8*)&Ae[e * 128 + kgp * 8] = v;
  }

  float msg[4][4];
#pragma unroll
  for (int m = 0; m < 4; ++m)
#pragma unroll
    for (int rr = 0; rr < 4; ++rr) msg[m][rr] = 0.f;

  __syncthreads();

  // opaque zero: A-LDS addresses depend on it -> reads can't be hoisted out
  // of the dg loop.
  int aoff = 0;
  asm volatile("" : "+v"(aoff));

  // B fragment base: lane row within chunk = fw*16+l15, k-offset q*8
  const _Float16* wb = WnnT + (size_t)(fw * 16 + l15) * 128 + q * 8;
  const int fcol = fw * 16 + l15;

  // explicit 2-deep register pipeline over the 16 dg groups
  f16x8 bb0[4][4], bb1[4][4];
  float bn0[4], bn1[4];
  loadB(bb0, bn0, wb, bnn, rot, fcol);

#pragma unroll 1
  for (int dgi = 0; dgi < 16; dgi += 2) {
    const int d0 = (dgi + rot) & 15;
    const int d1 = (dgi + 1 + rot) & 15;
    const int d2 = (dgi + 2 + rot) & 15;   // wraps on last iter (redundant, harmless)
    loadB(bb1, bn1, wb, bnn, d1, fcol);                 // prefetch dg+1
    computeB4(bb0, bn0, Ae, Hs, msg, d0, l15, q, aoff); // compute dg
    loadB(bb0, bn0, wb, bnn, d2, fcol);                 // prefetch dg+2
    computeB4(bb1, bn1, Ae, Hs, msg, d1, l15, q, aoff); // compute dg+1
  }

  // plain fp16 stores (no atomics) -> msgbuf[e][f]
#pragma unroll
  for (int m = 0; m < 4; ++m)
#pragma unroll
    for (int rr = 0; rr < 4; ++rr) {
      int e = ebase + m * 16 + q * 4 + rr;
      msgbuf[(size_t)e * 64 + fcol] = (_Float16)msg[m][rr];
    }
}

// ---------------------------------------------------------------------------
// node_update_g: agg via CSR gather of msgbuf; m = relu(agg + h@W_root+b);
// GRU gates gate-column-per-thread (weights read once per block); h (f32,
// d_out) updated in place. Block = 16 nodes, 256 threads.
// ---------------------------------------------------------------------------
__launch_bounds__(256)
__global__ void node_update_g(const _Float16* __restrict__ msgbuf,
                              const int* __restrict__ rowptr,
                              const int* __restrict__ eids,
                              float* __restrict__ hid,
                              const float* __restrict__ Wroot,
                              const float* __restrict__ bconv,
                              const float* __restrict__ wih,
                              const float* __restrict__ whh,
                              const float* __restrict__ bih,
                              const float* __restrict__ bhh) {
  __shared__ __align__(16) float shT[64 * 20];   // h^T  [k][nl], stride 20
  __shared__ __align__(16) float smT[64 * 20];   // m^T  [k][nl]
  __shared__ __align__(16) float sg[16 * 384];   // gates
  __shared__ __align__(16) float sW[64 * 64];    // Wroot
  const int t = threadIdx.x;
  const int nb = blockIdx.x * 16;

  // stage Wroot (f32, 16KB)
#pragma unroll
  for (int i = 0; i < 4; ++i) {
    int g = i * 256 + t;
    *(float4*)&sW[g * 4] = *(const float4*)&Wroot[g * 4];
  }
  // stage h transposed
#pragma unroll
  for (int i = 0; i < 4; ++i) {
    int idx = i * 256 + t;
    int nl = idx >> 6, dc = idx & 63;
    shT[dc * 20 + nl] = hid[(size_t)(nb + nl) * 64 + dc];
  }
  __syncthreads();

  // phase 1: gather msg + root matmul -> m (write transposed)
#pragma unroll
  for (int i = 0; i < 4; ++i) {
    int idx = i * 256 + t;
    int nl = idx >> 6, dc = idx & 63;
    int n = nb + nl;
    float acc = bconv[dc];
    int r0 = rowptr[n], r1 = rowptr[n + 1];
    for (int j = r0; j < r1; ++j)
      acc += (float)msgbuf[(size_t)eids[j] * 64 + dc];
    for (int k = 0; k < 64; ++k)
      acc = fmaf(shT[k * 20 + nl], sW[k * 64 + dc], acc);
    smT[dc * 20 + nl] = fmaxf(acc, 0.f);
  }
  __syncthreads();

  // phase 2: gates — thread owns one gate column, accumulates 16 nodes in regs
  for (int p = 0; p < 2; ++p) {
    int j2 = p * 256 + t;
    if (j2 < 384) {
      bool is_ih = (j2 < 192);
      int col = is_ih ? j2 : j2 - 192;
      const float* W = is_ih ? wih : whh;
      float bias = is_ih ? bih[col] : bhh[col];
      const float* inT = is_ih ? smT : shT;
      float a[16];
#pragma unroll
      for (int nl = 0; nl < 16; ++nl) a[nl] = bias;
      for (int k = 0; k < 64; ++k) {
        float wv = W[k * 192 + col];
        float4 v0 = *(const float4*)&inT[k * 20 + 0];
        float4 v1 = *(const float4*)&inT[k * 20 + 4];
        float4 v2 = *(const float4*)&inT[k * 20 + 8];
        float4 v3 = *(const float4*)&inT[k * 20 + 12];
        a[0]  = fmaf(v0.x, wv, a[0]);  a[1]  = fmaf(v0.y, wv, a[1]);
        a[2]  = fmaf(v0.z, wv, a[2]);  a[3]  = fmaf(v0.w, wv, a[3]);
        a[4]  = fmaf(v1.x, wv, a[4]);  a[5]  = fmaf(v1.y, wv, a[5]);
        a[6]  = fmaf(v1.z, wv, a[6]);  a[7]  = fmaf(v1.w, wv, a[7]);
        a[8]  = fmaf(v2.x, wv, a[8]);  a[9]  = fmaf(v2.y, wv, a[9]);
        a[10] = fmaf(v2.z, wv, a[10]); a[11] = fmaf(v2.w, wv, a[11]);
        a[12] = fmaf(v3.x, wv, a[12]); a[13] = fmaf(v3.y, wv, a[13]);
        a[14] = fmaf(v3.z, wv, a[14]); a[15] = fmaf(v3.w, wv, a[15]);
      }
#pragma unroll
      for (int nl = 0; nl < 16; ++nl) sg[nl * 384 + j2] = a[nl];
    }
  }
  __syncthreads();

  // phase 3: GRU elementwise
#pragma unroll
  for (int i = 0; i < 4; ++i) {
    int idx = i * 256 + t;
    int nl = idx >> 6, dc = idx & 63;
    const float* g = &sg[nl * 384];
    float ir = g[dc], iz = g[64 + dc], in_ = g[128 + dc];
    float hr = g[192 + dc], hz = g[256 + dc], hn = g[320 + dc];
    float r = sigm(ir + hr), z = sigm(iz + hz);
    float nc = tanhf(in_ + r * hn);
    hid[(size_t)nb * 64 + idx] = (1.f - z) * nc + z * shT[dc * 20 + nl];
  }
}

// ---------------------------------------------------------------------------
// edge_mlp (MFMA, fp16): e' = relu(relu([h[row]|h[col]|e] @ We1 + b1) @ We2 + b2)
// 64 edges/block. cat staged to LDS as fp16; B fragments direct from global
// (per-wave disjoint rows). Hidden tile Ts in LDS (fp16). f32 in/out, in place.
// ---------------------------------------------------------------------------
__launch_bounds__(256)
__global__ void edge_mlp_m(const float* __restrict__ hid,
                           float* __restrict__ ebf,
                           const int* __restrict__ eidx,
                           const _Float16* __restrict__ We1T,
                           const float* __restrict__ be1,
                           const _Float16* __restrict__ We2T,
                           const float* __restrict__ be2) {
  __shared__ _Float16 As[64 * 264];   // 33,792 B
  __shared__ _Float16 Ts[64 * 136];   // 17,408 B
  const int t = threadIdx.x;
  const int w = t >> 6, l = t & 63, l15 = l & 15, q = l >> 4;
  const int mbase = blockIdx.x * 64;

  for (int g = t; g < 2048; g += 256) {
    int r = g >> 5, kg = g & 31;
    int e = mbase + r;
    const float* src;
    if (kg < 8)       src = &hid[(size_t)eidx[e] * 64 + kg * 8];
    else if (kg < 16) src = &hid[(size_t)eidx[N_EDGES + e] * 64 + (kg - 8) * 8];
    else              src = &ebf[(size_t)e * 128 + (kg - 16) * 8];
    *(f16x8*)&As[r * 264 + kg * 8] = packh8(src);
  }
  __syncthreads();

  f32x4 zero4 = {0.f, 0.f, 0.f, 0.f};
  f32x4 acc[4][2];
#pragma unroll
  for (int m = 0; m < 4; ++m)
#pragma unroll
    for (int nn = 0; nn < 2; ++nn) acc[m][nn] = zero4;

#pragma unroll
  for (int kc = 0; kc < 4; ++kc)
#pragma unroll
    for (int kk = 0; kk < 2; ++kk) {
      int ko = kc * 64 + kk * 32 + q * 8;
      f16x8 b0 = *(const f16x8*)(We1T + (size_t)(w * 32 + l15) * 256 + ko);
      f16x8 b1 = *(const f16x8*)(We1T + (size_t)(w * 32 + 16 + l15) * 256 + ko);
#pragma unroll
      for (int m = 0; m < 4; ++m) {
        f16x8 a = *(const f16x8*)&As[(m * 16 + l15) * 264 + ko];
        acc[m][0] = __builtin_amdgcn_mfma_f32_16x16x32_f16(a, b0, acc[m][0], 0, 0, 0);
        acc[m][1] = __builtin_amdgcn_mfma_f32_16x16x32_f16(a, b1, acc[m][1], 0, 0, 0);
      }
    }

#pragma unroll
  for (int m = 0; m < 4; ++m)
#pragma unroll
    for (int nn = 0; nn < 2; ++nn) {
      int col = w * 32 + nn * 16 + l15;
      float bv = be1[col];
#pragma unroll
      for (int rr = 0; rr < 4; ++rr) {
        int row = m * 16 + q * 4 + rr;
        Ts[row * 136 + col] = (_Float16)fmaxf(acc[m][nn][rr] + bv, 0.f);
      }
    }
  __syncthreads();

  f32x4 acc2[4][2];
#pragma unroll
  for (int m = 0; m < 4; ++m)
#pragma unroll
    for (int nn = 0; nn < 2; ++nn) acc2[m][nn] = zero4;

#pragma unroll
  for (int kc = 0; kc < 2; ++kc)
#pragma unroll
    for (int kk = 0; kk < 2; ++kk) {
      int ko = kc * 64 + kk * 32 + q * 8;
      f16x8 b0 = *(const f16x8*)(We2T + (size_t)(w * 32 + l15) * 128 + ko);
      f16x8 b1 = *(const f16x8*)(We2T + (size_t)(w * 32 + 16 + l15) * 128 + ko);
#pragma unroll
      for (int m = 0; m < 4; ++m) {
        f16x8 a = *(const f16x8*)&Ts[(m * 16 + l15) * 136 + ko];
        acc2[m][0] = __builtin_amdgcn_mfma_f32_16x16x32_f16(a, b0, acc2[m][0], 0, 0, 0);
        acc2[m][1] = __builtin_amdgcn_mfma_f32_16x16x32_f16(a, b1, acc2[m][1], 0, 0, 0);
      }
    }

#pragma unroll
  for (int m = 0; m < 4; ++m)
#pragma unroll
    for (int nn = 0; nn < 2; ++nn) {
      int col = w * 32 + nn * 16 + l15;
      float bv = be2[col];
#pragma unroll
      for (int rr = 0; rr < 4; ++rr) {
        int row = mbase + m * 16 + q * 4 + rr;
        ebf[(size_t)row * 128 + col] = fmaxf(acc2[m][nn][rr] + bv, 0.f);
      }
    }
}

// ---------------------------------------------------------------------------
extern "C" void kernel_launch(void* const* d_in, const int* in_sizes, int n_in,
                              void* d_out, int out_size, void* d_ws, size_t ws_size,
                              hipStream_t stream) {
  const float* nf    = (const float*)d_in[0];
  const float* ea    = (const float*)d_in[1];
  const int*   eidx  = (const int*)d_in[2];
  const float* Wp    = (const float*)d_in[3];
  const float* bp    = (const float*)d_in[4];
  const float* Wpe   = (const float*)d_in[5];
  const float* bpe   = (const float*)d_in[6];
  const float* Wnn   = (const float*)d_in[7];
  const float* bnn   = (const float*)d_in[8];
  const float* Wroot = (const float*)d_in[9];
  const float* bconv = (const float*)d_in[10];
  const float* wih   = (const float*)d_in[11];
  const float* whh   = (const float*)d_in[12];
  const float* bih   = (const float*)d_in[13];
  const float* bhh   = (const float*)d_in[14];
  const float* We1   = (const float*)d_in[15];
  const float* be1   = (const float*)d_in[16];
  const float* We2   = (const float*)d_in[17];
  const float* be2   = (const float*)d_in[18];

  // h and e live in d_out (f32 masters), fully rewritten every launch.
  float* hid = (float*)d_out;                 // 4096*64
  float* ebf = (float*)d_out + 4096 * 64;     // 32768*128

  // workspace: 5,505,152 B
  char* ws = (char*)d_ws;
  _Float16* WnnT   = (_Float16*)(ws + 0);          // 1,048,576
  _Float16* We1T   = (_Float16*)(ws + 1048576);    //    65,536
  _Float16* We2T   = (_Float16*)(ws + 1114112);    //    32,768
  _Float16* msgbuf = (_Float16*)(ws + 1146880);    // 4,194,304
  int*      rowptr = (int*)(ws + 5341184);         //    16,512 (4097 used)
  int*      cursor = (int*)(ws + 5357696);         //    16,384
  int*      eids   = (int*)(ws + 5374080);         //   131,072

  prep_all<<<320, 256, 0, stream>>>(Wnn, We1, We2, WnnT, We1T, We2T);
  proj_node_f<<<1024, 256, 0, stream>>>(nf, Wp, bp, hid);
  proj_edge_f2<<<1024, 256, 0, stream>>>(ea, Wpe, bpe, ebf);

  // CSR of incoming edges per node (built once; edge_index is constant)
  csr_zero<<<16, 256, 0, stream>>>(cursor);          // use cursor as rowcnt
  csr_count<<<128, 256, 0, stream>>>(eidx, cursor);
  csr_scan<<<1, 1024, 0, stream>>>(cursor, rowptr, cursor);
  csr_fill<<<128, 256, 0, stream>>>(eidx, cursor, eids);

  for (int s = 0; s < 3; ++s) {
    fused_msg_m<<<512, 256, 0, stream>>>(ebf, hid, WnnT, bnn, eidx, msgbuf);
    node_update_g<<<256, 256, 0, stream>>>(msgbuf, rowptr, eids, hid, Wroot, bconv,
                                           wih, whh, bih, bhh);
    edge_mlp_m<<<512, 256, 0, stream>>>(hid, ebf, eidx, We1T, be1, We2T, be2);
  }
}

// Round 7
// 546.821 us; speedup vs baseline: 1.1040x; 1.1040x over previous
//
#include <hip/hip_runtime.h>
#include <stdint.h>

typedef __attribute__((ext_vector_type(8))) _Float16 f16x8;
typedef __attribute__((ext_vector_type(4))) float f32x4;

#define N_NODES 4096
#define N_EDGES 32768

__device__ __forceinline__ float sigm(float x) { return 1.f / (1.f + __expf(-x)); }

// pack 8 consecutive f32 -> f16x8 (RNE)
__device__ __forceinline__ f16x8 packh8(const float* p) {
  f16x8 r;
#pragma unroll
  for (int i = 0; i < 8; ++i) r[i] = (_Float16)p[i];
  return r;
}

// ---------------------------------------------------------------------------
// prep (merged): blocks 0..127  -> WnnT[n][k] fp16 from Wnn[k][n] f32
//                blocks 128..319 -> We1T / We2T fp16 transposes
// ---------------------------------------------------------------------------
__global__ void prep_all(const float* __restrict__ Wnn,
                         const float* __restrict__ We1,
                         const float* __restrict__ We2,
                         _Float16* __restrict__ WnnT,
                         _Float16* __restrict__ We1T,
                         _Float16* __restrict__ We2T) {
  __shared__ float tile[128][33];
  const int b = blockIdx.x, t = threadIdx.x;
  if (b < 128) {
    const int nb = b * 32;
    for (int i = 0; i < 16; ++i) {
      int g = i * 256 + t;          // 4096 = 128k x 32n
      int k = g >> 5, j = g & 31;
      tile[k][j] = Wnn[(size_t)k * 4096 + nb + j];
    }
    __syncthreads();
    for (int i = 0; i < 16; ++i) {
      int g = i * 256 + t;
      int j = g >> 7, k = g & 127;
      WnnT[(size_t)(nb + j) * 128 + k] = (_Float16)tile[k][j];
    }
  } else {
    int idx = (b - 128) * 256 + t;   // < 49152
    if (idx < 32768) {
      int n = idx >> 8, k = idx & 255;
      We1T[idx] = (_Float16)We1[(size_t)k * 128 + n];
    } else {
      int j = idx - 32768;
      int n = j >> 7, k = j & 127;
      We2T[j] = (_Float16)We2[(size_t)k * 128 + n];
    }
  }
}

// ---------------------------------------------------------------------------
// CSR build (once per launch; edge_index is launch-constant)
// ---------------------------------------------------------------------------
__global__ void csr_zero(int* __restrict__ rowcnt) {
  rowcnt[blockIdx.x * 256 + threadIdx.x] = 0;
}
__global__ void csr_count(const int* __restrict__ eidx, int* __restrict__ rowcnt) {
  int e = blockIdx.x * 256 + threadIdx.x;
  atomicAdd(&rowcnt[eidx[N_EDGES + e]], 1);
}
__global__ void csr_scan(const int* __restrict__ rowcnt,
                         int* __restrict__ rowptr, int* __restrict__ cursor) {
  __shared__ int part[1024];
  const int t = threadIdx.x;
  const int base = t * 4;
  int s0 = rowcnt[base], s1 = rowcnt[base + 1], s2 = rowcnt[base + 2], s3 = rowcnt[base + 3];
  int sum = s0 + s1 + s2 + s3;
  part[t] = sum;
  __syncthreads();
  for (int off = 1; off < 1024; off <<= 1) {
    int v = (t >= off) ? part[t - off] : 0;
    __syncthreads();
    part[t] += v;
    __syncthreads();
  }
  int excl = part[t] - sum;
  int p0 = excl, p1 = excl + s0, p2 = excl + s0 + s1, p3 = excl + s0 + s1 + s2;
  rowptr[base] = p0; rowptr[base + 1] = p1; rowptr[base + 2] = p2; rowptr[base + 3] = p3;
  cursor[base] = p0; cursor[base + 1] = p1; cursor[base + 2] = p2; cursor[base + 3] = p3;
  if (t == 0) rowptr[4096] = N_EDGES;
}
__global__ void csr_fill(const int* __restrict__ eidx, int* __restrict__ cursor,
                         int* __restrict__ eids) {
  int e = blockIdx.x * 256 + threadIdx.x;
  int slot = atomicAdd(&cursor[eidx[N_EDGES + e]], 1);
  eids[slot] = e;
}

// ---------------------------------------------------------------------------
// proj_node: h = relu(node_feats @ W_p + b_p) -> hid f32 (in d_out)
// ---------------------------------------------------------------------------
__global__ void proj_node_f(const float* __restrict__ nf,
                            const float* __restrict__ Wp,
                            const float* __restrict__ bp,
                            float* __restrict__ h) {
  int idx = blockIdx.x * 256 + threadIdx.x;
  int n = idx >> 6, c = idx & 63;
  float acc = bp[c];
  for (int k = 0; k < 64; ++k)
    acc = fmaf(nf[n * 64 + k], Wp[k * 64 + c], acc);
  h[idx] = fmaxf(acc, 0.f);
}

// ---------------------------------------------------------------------------
// proj_edge: e = relu(edge_attr @ W_pe + b_pe); Wpe cached in LDS; 32 e/block.
// ---------------------------------------------------------------------------
__launch_bounds__(256)
__global__ void proj_edge_f2(const float* __restrict__ ea,
                             const float* __restrict__ Wpe,
                             const float* __restrict__ bpe,
                             float* __restrict__ e) {
  __shared__ float sw[16 * 128];
  __shared__ float sb[128];
  __shared__ float sa[32][17];
  const int t = threadIdx.x;
  const int ebase = blockIdx.x * 32;
  for (int g = t; g < 2048; g += 256) sw[g] = Wpe[g];
  if (t < 128) sb[t] = bpe[t];
  for (int g = t; g < 512; g += 256) {
    int r = g >> 4, k = g & 15;
    sa[r][k] = ea[(size_t)(ebase + r) * 16 + k];
  }
  __syncthreads();
  int c = t & 127, eg = t >> 7;
  float wc[16];
#pragma unroll
  for (int k = 0; k < 16; ++k) wc[k] = sw[k * 128 + c];
  float bv = sb[c];
#pragma unroll
  for (int i = 0; i < 16; ++i) {
    int ee = eg * 16 + i;
    float acc = bv;
#pragma unroll
    for (int k = 0; k < 16; ++k) acc = fmaf(sa[ee][k], wc[k], acc);
    e[(size_t)(ebase + ee) * 128 + c] = fmaxf(acc, 0.f);
  }
}

// ---------------------------------------------------------------------------
// fused_msg (MFMA fp16 v15): 512 blocks x 256 threads (4 waves), 64 e/block.
// R18 post-mortem: v14's (256,2) re-imposed a 128-VGPR cap (4th cap+spill:
// VGPR exactly 128, FETCH 77MB/WRITE 94MB). Empirical rule across 7 runs:
// ONLY __launch_bounds__(<=256 threads, 1) grants the full 256-VGPR arch
// budget; any other config caps at 128 or 64 and spills this body.
// R5 ((256,1), msg[8][4]) allocated 256 but natural demand ~290 -> small
// spill. v15 = v14 body (msg[4][4], ~200 VGPR natural) + (256,1):
// first clean, unspilled run of the B double-buffer pipeline.
// 2 waves/SIMD, 2 blocks/CU (LDS 33.8KB) = v8's 8 waves/CU + latency hiding.
// Kept: per-wave dg rotation, opaque A-LDS offset, bnn in MFMA C-init,
// XOR-swizzled Ae.
// ---------------------------------------------------------------------------
__device__ __forceinline__ void loadB(f16x8 (&BB)[4][4], float (&BN)[4],
                                      const _Float16* __restrict__ wb,
                                      const float* __restrict__ bnn,
                                      int dgr, int fcol) {
#pragma unroll
  for (int c = 0; c < 4; ++c) {
    const _Float16* p = wb + (size_t)(dgr * 4 + c) * 8192;
#pragma unroll
    for (int kk = 0; kk < 4; ++kk) BB[c][kk] = *(const f16x8*)(p + kk * 32);
    BN[c] = bnn[(dgr * 4 + c) * 64 + fcol];
  }
}

__device__ __forceinline__ void computeB4(const f16x8 (&BB)[4][4], const float (&BN)[4],
                                          const _Float16* __restrict__ Ae,
                                          const float* __restrict__ Hs,
                                          float (&msg)[4][4],
                                          int dgr, int l15, int q, int aoff) {
#pragma unroll
  for (int m = 0; m < 4; ++m) {
    const int arow = (m * 16 + l15) * 128 + aoff;
    f32x4 C[4];
#pragma unroll
    for (int c = 0; c < 4; ++c)
      C[c] = (f32x4){BN[c], BN[c], BN[c], BN[c]};   // bias pre-loaded
#pragma unroll
    for (int kk = 0; kk < 4; ++kk) {
      int kgp = (kk * 4 + q) ^ l15;   // e&15 == l15 for A rows
      f16x8 a = *(const f16x8*)&Ae[arow + kgp * 8];
#pragma unroll
      for (int c = 0; c < 4; ++c)
        C[c] = __builtin_amdgcn_mfma_f32_16x16x32_f16(a, BB[c][kk], C[c], 0, 0, 0);
    }
#pragma unroll
    for (int c = 0; c < 4; ++c) {
      int d = dgr * 4 + c;
      float4 hv = *(const float4*)&Hs[d * 68 + m * 16 + q * 4];
      msg[m][0] = fmaf(hv.x, fmaxf(C[c][0], 0.f), msg[m][0]);
      msg[m][1] = fmaf(hv.y, fmaxf(C[c][1], 0.f), msg[m][1]);
      msg[m][2] = fmaf(hv.z, fmaxf(C[c][2], 0.f), msg[m][2]);
      msg[m][3] = fmaf(hv.w, fmaxf(C[c][3], 0.f), msg[m][3]);
    }
  }
}

__launch_bounds__(256, 1)
__global__ void fused_msg_m(const float* __restrict__ ebf,
                            const float* __restrict__ hid,
                            const _Float16* __restrict__ WnnT,
                            const float* __restrict__ bnn,
                            const int* __restrict__ eidx,
                            _Float16* __restrict__ msgbuf) {
  __shared__ __align__(16) _Float16 Ae[64 * 128];  // 16,384 B, XOR-swizzled
  __shared__ __align__(16) float Hs[64 * 68];      // 17,408 B  Hs[d*68+e]
  const int t = threadIdx.x;       // 0..255
  const int w = t >> 6, l = t & 63, l15 = l & 15, q = l >> 4;
  const int fw = w;                // f cols: fw*16 + l15 (4 waves = 4 f-groups)
  const int ebase = blockIdx.x * 64;
  const int rot = (blockIdx.x * 4 + w) & 15;   // per-WAVE rotation

  // stage Hs (transposed): 64 e x 16 d-quads
#pragma unroll
  for (int i = 0; i < 4; ++i) {
    int g = i * 256 + t;           // 1024 = 64 e x 16 d4
    int e = g >> 4, d4 = g & 15;
    int r = eidx[ebase + e];
    float4 v = *(const float4*)&hid[(size_t)r * 64 + d4 * 4];
    Hs[(d4 * 4 + 0) * 68 + e] = v.x;
    Hs[(d4 * 4 + 1) * 68 + e] = v.y;
    Hs[(d4 * 4 + 2) * 68 + e] = v.z;
    Hs[(d4 * 4 + 3) * 68 + e] = v.w;
  }
  // stage Ae: 64 edges x 128 k, f32 -> fp16 once, XOR-swizzled 16B blocks
#pragma unroll
  for (int i = 0; i < 4; ++i) {
    int g = i * 256 + t;           // 1024 = 64 e x 16 groups of 8 halves
    int e = g >> 4, kg = g & 15;
    f16x8 v = packh8(&ebf[(size_t)(ebase + e) * 128 + kg * 8]);
    int kgp = kg ^ (e & 15);
    *(f16x8*)&Ae[e * 128 + kgp * 8] = v;
  }

  float msg[4][4];
#pragma unroll
  for (int m = 0; m < 4; ++m)
#pragma unroll
    for (int rr = 0; rr < 4; ++rr) msg[m][rr] = 0.f;

  __syncthreads();

  // opaque zero: A-LDS addresses depend on it -> reads can't be hoisted out
  // of the dg loop.
  int aoff = 0;
  asm volatile("" : "+v"(aoff));

  // B fragment base: lane row within chunk = fw*16+l15, k-offset q*8
  const _Float16* wb = WnnT + (size_t)(fw * 16 + l15) * 128 + q * 8;
  const int fcol = fw * 16 + l15;

  // explicit 2-deep register pipeline over the 16 dg groups
  f16x8 bb0[4][4], bb1[4][4];
  float bn0[4], bn1[4];
  loadB(bb0, bn0, wb, bnn, rot, fcol);

#pragma unroll 1
  for (int dgi = 0; dgi < 16; dgi += 2) {
    const int d0 = (dgi + rot) & 15;
    const int d1 = (dgi + 1 + rot) & 15;
    const int d2 = (dgi + 2 + rot) & 15;   // wraps on last iter (redundant, harmless)
    loadB(bb1, bn1, wb, bnn, d1, fcol);                 // prefetch dg+1
    computeB4(bb0, bn0, Ae, Hs, msg, d0, l15, q, aoff); // compute dg
    loadB(bb0, bn0, wb, bnn, d2, fcol);                 // prefetch dg+2
    computeB4(bb1, bn1, Ae, Hs, msg, d1, l15, q, aoff); // compute dg+1
  }

  // plain fp16 stores (no atomics) -> msgbuf[e][f]
#pragma unroll
  for (int m = 0; m < 4; ++m)
#pragma unroll
    for (int rr = 0; rr < 4; ++rr) {
      int e = ebase + m * 16 + q * 4 + rr;
      msgbuf[(size_t)e * 64 + fcol] = (_Float16)msg[m][rr];
    }
}

// ---------------------------------------------------------------------------
// node_update_g: agg via CSR gather of msgbuf; m = relu(agg + h@W_root+b);
// GRU gates gate-column-per-thread (weights read once per block); h (f32,
// d_out) updated in place. Block = 16 nodes, 256 threads.
// ---------------------------------------------------------------------------
__launch_bounds__(256)
__global__ void node_update_g(const _Float16* __restrict__ msgbuf,
                              const int* __restrict__ rowptr,
                              const int* __restrict__ eids,
                              float* __restrict__ hid,
                              const float* __restrict__ Wroot,
                              const float* __restrict__ bconv,
                              const float* __restrict__ wih,
                              const float* __restrict__ whh,
                              const float* __restrict__ bih,
                              const float* __restrict__ bhh) {
  __shared__ __align__(16) float shT[64 * 20];   // h^T  [k][nl], stride 20
  __shared__ __align__(16) float smT[64 * 20];   // m^T  [k][nl]
  __shared__ __align__(16) float sg[16 * 384];   // gates
  __shared__ __align__(16) float sW[64 * 64];    // Wroot
  const int t = threadIdx.x;
  const int nb = blockIdx.x * 16;

  // stage Wroot (f32, 16KB)
#pragma unroll
  for (int i = 0; i < 4; ++i) {
    int g = i * 256 + t;
    *(float4*)&sW[g * 4] = *(const float4*)&Wroot[g * 4];
  }
  // stage h transposed
#pragma unroll
  for (int i = 0; i < 4; ++i) {
    int idx = i * 256 + t;
    int nl = idx >> 6, dc = idx & 63;
    shT[dc * 20 + nl] = hid[(size_t)(nb + nl) * 64 + dc];
  }
  __syncthreads();

  // phase 1: gather msg + root matmul -> m (write transposed)
#pragma unroll
  for (int i = 0; i < 4; ++i) {
    int idx = i * 256 + t;
    int nl = idx >> 6, dc = idx & 63;
    int n = nb + nl;
    float acc = bconv[dc];
    int r0 = rowptr[n], r1 = rowptr[n + 1];
    for (int j = r0; j < r1; ++j)
      acc += (float)msgbuf[(size_t)eids[j] * 64 + dc];
    for (int k = 0; k < 64; ++k)
      acc = fmaf(shT[k * 20 + nl], sW[k * 64 + dc], acc);
    smT[dc * 20 + nl] = fmaxf(acc, 0.f);
  }
  __syncthreads();

  // phase 2: gates — thread owns one gate column, accumulates 16 nodes in regs
  for (int p = 0; p < 2; ++p) {
    int j2 = p * 256 + t;
    if (j2 < 384) {
      bool is_ih = (j2 < 192);
      int col = is_ih ? j2 : j2 - 192;
      const float* W = is_ih ? wih : whh;
      float bias = is_ih ? bih[col] : bhh[col];
      const float* inT = is_ih ? smT : shT;
      float a[16];
#pragma unroll
      for (int nl = 0; nl < 16; ++nl) a[nl] = bias;
      for (int k = 0; k < 64; ++k) {
        float wv = W[k * 192 + col];
        float4 v0 = *(const float4*)&inT[k * 20 + 0];
        float4 v1 = *(const float4*)&inT[k * 20 + 4];
        float4 v2 = *(const float4*)&inT[k * 20 + 8];
        float4 v3 = *(const float4*)&inT[k * 20 + 12];
        a[0]  = fmaf(v0.x, wv, a[0]);  a[1]  = fmaf(v0.y, wv, a[1]);
        a[2]  = fmaf(v0.z, wv, a[2]);  a[3]  = fmaf(v0.w, wv, a[3]);
        a[4]  = fmaf(v1.x, wv, a[4]);  a[5]  = fmaf(v1.y, wv, a[5]);
        a[6]  = fmaf(v1.z, wv, a[6]);  a[7]  = fmaf(v1.w, wv, a[7]);
        a[8]  = fmaf(v2.x, wv, a[8]);  a[9]  = fmaf(v2.y, wv, a[9]);
        a[10] = fmaf(v2.z, wv, a[10]); a[11] = fmaf(v2.w, wv, a[11]);
        a[12] = fmaf(v3.x, wv, a[12]); a[13] = fmaf(v3.y, wv, a[13]);
        a[14] = fmaf(v3.z, wv, a[14]); a[15] = fmaf(v3.w, wv, a[15]);
      }
#pragma unroll
      for (int nl = 0; nl < 16; ++nl) sg[nl * 384 + j2] = a[nl];
    }
  }
  __syncthreads();

  // phase 3: GRU elementwise
#pragma unroll
  for (int i = 0; i < 4; ++i) {
    int idx = i * 256 + t;
    int nl = idx >> 6, dc = idx & 63;
    const float* g = &sg[nl * 384];
    float ir = g[dc], iz = g[64 + dc], in_ = g[128 + dc];
    float hr = g[192 + dc], hz = g[256 + dc], hn = g[320 + dc];
    float r = sigm(ir + hr), z = sigm(iz + hz);
    float nc = tanhf(in_ + r * hn);
    hid[(size_t)nb * 64 + idx] = (1.f - z) * nc + z * shT[dc * 20 + nl];
  }
}

// ---------------------------------------------------------------------------
// edge_mlp (MFMA, fp16): e' = relu(relu([h[row]|h[col]|e] @ We1 + b1) @ We2 + b2)
// 64 edges/block. cat staged to LDS as fp16; B fragments direct from global
// (per-wave disjoint rows). Hidden tile Ts in LDS (fp16). f32 in/out, in place.
// ---------------------------------------------------------------------------
__launch_bounds__(256)
__global__ void edge_mlp_m(const float* __restrict__ hid,
                           float* __restrict__ ebf,
                           const int* __restrict__ eidx,
                           const _Float16* __restrict__ We1T,
                           const float* __restrict__ be1,
                           const _Float16* __restrict__ We2T,
                           const float* __restrict__ be2) {
  __shared__ _Float16 As[64 * 264];   // 33,792 B
  __shared__ _Float16 Ts[64 * 136];   // 17,408 B
  const int t = threadIdx.x;
  const int w = t >> 6, l = t & 63, l15 = l & 15, q = l >> 4;
  const int mbase = blockIdx.x * 64;

  for (int g = t; g < 2048; g += 256) {
    int r = g >> 5, kg = g & 31;
    int e = mbase + r;
    const float* src;
    if (kg < 8)       src = &hid[(size_t)eidx[e] * 64 + kg * 8];
    else if (kg < 16) src = &hid[(size_t)eidx[N_EDGES + e] * 64 + (kg - 8) * 8];
    else              src = &ebf[(size_t)e * 128 + (kg - 16) * 8];
    *(f16x8*)&As[r * 264 + kg * 8] = packh8(src);
  }
  __syncthreads();

  f32x4 zero4 = {0.f, 0.f, 0.f, 0.f};
  f32x4 acc[4][2];
#pragma unroll
  for (int m = 0; m < 4; ++m)
#pragma unroll
    for (int nn = 0; nn < 2; ++nn) acc[m][nn] = zero4;

#pragma unroll
  for (int kc = 0; kc < 4; ++kc)
#pragma unroll
    for (int kk = 0; kk < 2; ++kk) {
      int ko = kc * 64 + kk * 32 + q * 8;
      f16x8 b0 = *(const f16x8*)(We1T + (size_t)(w * 32 + l15) * 256 + ko);
      f16x8 b1 = *(const f16x8*)(We1T + (size_t)(w * 32 + 16 + l15) * 256 + ko);
#pragma unroll
      for (int m = 0; m < 4; ++m) {
        f16x8 a = *(const f16x8*)&As[(m * 16 + l15) * 264 + ko];
        acc[m][0] = __builtin_amdgcn_mfma_f32_16x16x32_f16(a, b0, acc[m][0], 0, 0, 0);
        acc[m][1] = __builtin_amdgcn_mfma_f32_16x16x32_f16(a, b1, acc[m][1], 0, 0, 0);
      }
    }

#pragma unroll
  for (int m = 0; m < 4; ++m)
#pragma unroll
    for (int nn = 0; nn < 2; ++nn) {
      int col = w * 32 + nn * 16 + l15;
      float bv = be1[col];
#pragma unroll
      for (int rr = 0; rr < 4; ++rr) {
        int row = m * 16 + q * 4 + rr;
        Ts[row * 136 + col] = (_Float16)fmaxf(acc[m][nn][rr] + bv, 0.f);
      }
    }
  __syncthreads();

  f32x4 acc2[4][2];
#pragma unroll
  for (int m = 0; m < 4; ++m)
#pragma unroll
    for (int nn = 0; nn < 2; ++nn) acc2[m][nn] = zero4;

#pragma unroll
  for (int kc = 0; kc < 2; ++kc)
#pragma unroll
    for (int kk = 0; kk < 2; ++kk) {
      int ko = kc * 64 + kk * 32 + q * 8;
      f16x8 b0 = *(const f16x8*)(We2T + (size_t)(w * 32 + l15) * 128 + ko);
      f16x8 b1 = *(const f16x8*)(We2T + (size_t)(w * 32 + 16 + l15) * 128 + ko);
#pragma unroll
      for (int m = 0; m < 4; ++m) {
        f16x8 a = *(const f16x8*)&Ts[(m * 16 + l15) * 136 + ko];
        acc2[m][0] = __builtin_amdgcn_mfma_f32_16x16x32_f16(a, b0, acc2[m][0], 0, 0, 0);
        acc2[m][1] = __builtin_amdgcn_mfma_f32_16x16x32_f16(a, b1, acc2[m][1], 0, 0, 0);
      }
    }

#pragma unroll
  for (int m = 0; m < 4; ++m)
#pragma unroll
    for (int nn = 0; nn < 2; ++nn) {
      int col = w * 32 + nn * 16 + l15;
      float bv = be2[col];
#pragma unroll
      for (int rr = 0; rr < 4; ++rr) {
        int row = mbase + m * 16 + q * 4 + rr;
        ebf[(size_t)row * 128 + col] = fmaxf(acc2[m][nn][rr] + bv, 0.f);
      }
    }
}

// ---------------------------------------------------------------------------
extern "C" void kernel_launch(void* const* d_in, const int* in_sizes, int n_in,
                              void* d_out, int out_size, void* d_ws, size_t ws_size,
                              hipStream_t stream) {
  const float* nf    = (const float*)d_in[0];
  const float* ea    = (const float*)d_in[1];
  const int*   eidx  = (const int*)d_in[2];
  const float* Wp    = (const float*)d_in[3];
  const float* bp    = (const float*)d_in[4];
  const float* Wpe   = (const float*)d_in[5];
  const float* bpe   = (const float*)d_in[6];
  const float* Wnn   = (const float*)d_in[7];
  const float* bnn   = (const float*)d_in[8];
  const float* Wroot = (const float*)d_in[9];
  const float* bconv = (const float*)d_in[10];
  const float* wih   = (const float*)d_in[11];
  const float* whh   = (const float*)d_in[12];
  const float* bih   = (const float*)d_in[13];
  const float* bhh   = (const float*)d_in[14];
  const float* We1   = (const float*)d_in[15];
  const float* be1   = (const float*)d_in[16];
  const float* We2   = (const float*)d_in[17];
  const float* be2   = (const float*)d_in[18];

  // h and e live in d_out (f32 masters), fully rewritten every launch.
  float* hid = (float*)d_out;                 // 4096*64
  float* ebf = (float*)d_out + 4096 * 64;     // 32768*128

  // workspace: 5,505,152 B
  char* ws = (char*)d_ws;
  _Float16* WnnT   = (_Float16*)(ws + 0);          // 1,048,576
  _Float16* We1T   = (_Float16*)(ws + 1048576);    //    65,536
  _Float16* We2T   = (_Float16*)(ws + 1114112);    //    32,768
  _Float16* msgbuf = (_Float16*)(ws + 1146880);    // 4,194,304
  int*      rowptr = (int*)(ws + 5341184);         //    16,512 (4097 used)
  int*      cursor = (int*)(ws + 5357696);         //    16,384
  int*      eids   = (int*)(ws + 5374080);         //   131,072

  prep_all<<<320, 256, 0, stream>>>(Wnn, We1, We2, WnnT, We1T, We2T);
  proj_node_f<<<1024, 256, 0, stream>>>(nf, Wp, bp, hid);
  proj_edge_f2<<<1024, 256, 0, stream>>>(ea, Wpe, bpe, ebf);

  // CSR of incoming edges per node (built once; edge_index is constant)
  csr_zero<<<16, 256, 0, stream>>>(cursor);          // use cursor as rowcnt
  csr_count<<<128, 256, 0, stream>>>(eidx, cursor);
  csr_scan<<<1, 1024, 0, stream>>>(cursor, rowptr, cursor);
  csr_fill<<<128, 256, 0, stream>>>(eidx, cursor, eids);

  for (int s = 0; s < 3; ++s) {
    fused_msg_m<<<512, 256, 0, stream>>>(ebf, hid, WnnT, bnn, eidx, msgbuf);
    node_update_g<<<256, 256, 0, stream>>>(msgbuf, rowptr, eids, hid, Wroot, bconv,
                                           wih, whh, bih, bhh);
    edge_mlp_m<<<512, 256, 0, stream>>>(hid, ebf, eidx, We1T, be1, We2T, be2);
  }
}

// Round 8
// 472.539 us; speedup vs baseline: 1.2775x; 1.1572x over previous
//
#include <hip/hip_runtime.h>
#include <stdint.h>

typedef __attribute__((ext_vector_type(8))) _Float16 f16x8;
typedef __attribute__((ext_vector_type(4))) float f32x4;

#define N_NODES 4096
#define N_EDGES 32768

__device__ __forceinline__ float sigm(float x) { return 1.f / (1.f + __expf(-x)); }

// pack 8 consecutive f32 -> f16x8 (RNE)
__device__ __forceinline__ f16x8 packh8(const float* p) {
  f16x8 r;
#pragma unroll
  for (int i = 0; i < 8; ++i) r[i] = (_Float16)p[i];
  return r;
}

// ---------------------------------------------------------------------------
// prep (merged): blocks 0..127  -> WnnT[n][k] fp16 from Wnn[k][n] f32
//                blocks 128..319 -> We1T / We2T fp16 transposes
// ---------------------------------------------------------------------------
__global__ void prep_all(const float* __restrict__ Wnn,
                         const float* __restrict__ We1,
                         const float* __restrict__ We2,
                         _Float16* __restrict__ WnnT,
                         _Float16* __restrict__ We1T,
                         _Float16* __restrict__ We2T) {
  __shared__ float tile[128][33];
  const int b = blockIdx.x, t = threadIdx.x;
  if (b < 128) {
    const int nb = b * 32;
    for (int i = 0; i < 16; ++i) {
      int g = i * 256 + t;          // 4096 = 128k x 32n
      int k = g >> 5, j = g & 31;
      tile[k][j] = Wnn[(size_t)k * 4096 + nb + j];
    }
    __syncthreads();
    for (int i = 0; i < 16; ++i) {
      int g = i * 256 + t;
      int j = g >> 7, k = g & 127;
      WnnT[(size_t)(nb + j) * 128 + k] = (_Float16)tile[k][j];
    }
  } else {
    int idx = (b - 128) * 256 + t;   // < 49152
    if (idx < 32768) {
      int n = idx >> 8, k = idx & 255;
      We1T[idx] = (_Float16)We1[(size_t)k * 128 + n];
    } else {
      int j = idx - 32768;
      int n = j >> 7, k = j & 127;
      We2T[j] = (_Float16)We2[(size_t)k * 128 + n];
    }
  }
}

// ---------------------------------------------------------------------------
// merged: blocks 0..15 -> zero CSR cursor; blocks 16..1039 -> proj_node
// h = relu(node_feats @ W_p + b_p) -> hid f32 (in d_out)
// ---------------------------------------------------------------------------
__global__ void zero_projnode(const float* __restrict__ nf,
                              const float* __restrict__ Wp,
                              const float* __restrict__ bp,
                              float* __restrict__ h,
                              int* __restrict__ rowcnt) {
  const int b = blockIdx.x, t = threadIdx.x;
  if (b < 16) {
    rowcnt[b * 256 + t] = 0;
    return;
  }
  int idx = (b - 16) * 256 + t;
  int n = idx >> 6, c = idx & 63;
  float acc = bp[c];
  for (int k = 0; k < 64; ++k)
    acc = fmaf(nf[n * 64 + k], Wp[k * 64 + c], acc);
  h[idx] = fmaxf(acc, 0.f);
}

// ---------------------------------------------------------------------------
// merged: blocks 0..127 -> CSR count; blocks 128..1151 -> proj_edge
// e = relu(edge_attr @ W_pe + b_pe); Wpe cached in LDS; 32 e/block.
// ---------------------------------------------------------------------------
__launch_bounds__(256)
__global__ void count_projedge(const float* __restrict__ ea,
                               const float* __restrict__ Wpe,
                               const float* __restrict__ bpe,
                               float* __restrict__ e,
                               const int* __restrict__ eidx,
                               int* __restrict__ rowcnt) {
  __shared__ float sw[16 * 128];
  __shared__ float sb[128];
  __shared__ float sa[32][17];
  const int b = blockIdx.x, t = threadIdx.x;
  if (b < 128) {
    int ed = b * 256 + t;
    atomicAdd(&rowcnt[eidx[N_EDGES + ed]], 1);
    return;
  }
  const int ebase = (b - 128) * 32;
  for (int g = t; g < 2048; g += 256) sw[g] = Wpe[g];
  if (t < 128) sb[t] = bpe[t];
  for (int g = t; g < 512; g += 256) {
    int r = g >> 4, k = g & 15;
    sa[r][k] = ea[(size_t)(ebase + r) * 16 + k];
  }
  __syncthreads();
  int c = t & 127, eg = t >> 7;
  float wc[16];
#pragma unroll
  for (int k = 0; k < 16; ++k) wc[k] = sw[k * 128 + c];
  float bv = sb[c];
#pragma unroll
  for (int i = 0; i < 16; ++i) {
    int ee = eg * 16 + i;
    float acc = bv;
#pragma unroll
    for (int k = 0; k < 16; ++k) acc = fmaf(sa[ee][k], wc[k], acc);
    e[(size_t)(ebase + ee) * 128 + c] = fmaxf(acc, 0.f);
  }
}

// ---------------------------------------------------------------------------
// CSR scan + fill (edge_index is launch-constant)
// ---------------------------------------------------------------------------
__global__ void csr_scan(const int* __restrict__ rowcnt,
                         int* __restrict__ rowptr, int* __restrict__ cursor) {
  __shared__ int part[1024];
  const int t = threadIdx.x;
  const int base = t * 4;
  int s0 = rowcnt[base], s1 = rowcnt[base + 1], s2 = rowcnt[base + 2], s3 = rowcnt[base + 3];
  int sum = s0 + s1 + s2 + s3;
  part[t] = sum;
  __syncthreads();
  for (int off = 1; off < 1024; off <<= 1) {
    int v = (t >= off) ? part[t - off] : 0;
    __syncthreads();
    part[t] += v;
    __syncthreads();
  }
  int excl = part[t] - sum;
  int p0 = excl, p1 = excl + s0, p2 = excl + s0 + s1, p3 = excl + s0 + s1 + s2;
  rowptr[base] = p0; rowptr[base + 1] = p1; rowptr[base + 2] = p2; rowptr[base + 3] = p3;
  cursor[base] = p0; cursor[base + 1] = p1; cursor[base + 2] = p2; cursor[base + 3] = p3;
  if (t == 0) rowptr[4096] = N_EDGES;
}
__global__ void csr_fill(const int* __restrict__ eidx, int* __restrict__ cursor,
                         int* __restrict__ eids) {
  int e = blockIdx.x * 256 + threadIdx.x;
  int slot = atomicAdd(&cursor[eidx[N_EDGES + e]], 1);
  eids[slot] = e;
}

// ---------------------------------------------------------------------------
// fused_msg (MFMA fp16 v8 RESTORED): 256 blocks x 512 threads.
// R19 decision: after 7 rounds of occupancy/pipeline variants (all 72-125us;
// clean unspilled dbuf pipeline = 102us, SLOWER), v8's structure is the
// empirical optimum for this shape: 8 waves (4 fw x 2 eh), eh-pairs L1-share
// B fragments, 2 waves/SIMD co-schedule MFMA vs VALU. Plateau accepted.
// ---------------------------------------------------------------------------
__launch_bounds__(512, 1)
__global__ void fused_msg_m(const float* __restrict__ ebf,
                            const float* __restrict__ hid,
                            const _Float16* __restrict__ WnnT,
                            const float* __restrict__ bnn,
                            const int* __restrict__ eidx,
                            _Float16* __restrict__ msgbuf) {
  __shared__ __align__(16) _Float16 Ae[128 * 128];  // 32,768 B, XOR-swizzled
  __shared__ __align__(16) float Hs[64 * 132];      // 33,792 B  Hs[d*132+e]
  const int t = threadIdx.x;       // 0..511
  const int w = t >> 6, l = t & 63, l15 = l & 15, q = l >> 4;
  const int fw = w & 3;            // f cols: fw*16 + l15
  const int eh = w >> 2;           // e half: eh*64
  const int ebase = blockIdx.x * 128;
  const int rot = (blockIdx.x * 2 + w) & 15;   // per-WAVE rotation

  // stage Hs (transposed): 128 e x 16 d-quads
#pragma unroll
  for (int i = 0; i < 4; ++i) {
    int g = i * 512 + t;
    int e = g >> 4, d4 = g & 15;
    int r = eidx[ebase + e];
    float4 v = *(const float4*)&hid[(size_t)r * 64 + d4 * 4];
    Hs[(d4 * 4 + 0) * 132 + e] = v.x;
    Hs[(d4 * 4 + 1) * 132 + e] = v.y;
    Hs[(d4 * 4 + 2) * 132 + e] = v.z;
    Hs[(d4 * 4 + 3) * 132 + e] = v.w;
  }
  // stage Ae: 128 edges x 128 k, f32 -> fp16 once, XOR-swizzled 16B blocks
#pragma unroll
  for (int i = 0; i < 4; ++i) {
    int g = i * 512 + t;           // 2048 = 128 e x 16 groups of 8 halves
    int e = g >> 4, kg = g & 15;
    f16x8 v = packh8(&ebf[(size_t)(ebase + e) * 128 + kg * 8]);
    int kgp = kg ^ (e & 15);
    *(f16x8*)&Ae[e * 128 + kgp * 8] = v;
  }

  float msg[4][4];
#pragma unroll
  for (int m = 0; m < 4; ++m)
#pragma unroll
    for (int rr = 0; rr < 4; ++rr) msg[m][rr] = 0.f;

  __syncthreads();

  // opaque zero: A-LDS addresses depend on it -> reads can't be hoisted out
  // of the dg loop (avoids the 64-VGPR A-hoist), but B loads CAN pipeline.
  int aoff = 0;
  asm volatile("" : "+v"(aoff));

  // B fragment base: lane row within chunk = fw*16+l15, k-offset q*8
  const _Float16* wb = WnnT + (size_t)(fw * 16 + l15) * 128 + q * 8;

#pragma unroll 1
  for (int dgi = 0; dgi < 16; ++dgi) {
    const int dgr = (dgi + rot) & 15;   // per-wave de-correlated B sweep
    f16x8 bb[4][4];
#pragma unroll
    for (int c = 0; c < 4; ++c) {
      const _Float16* p = wb + (size_t)(dgr * 4 + c) * 8192;
#pragma unroll
      for (int kk = 0; kk < 4; ++kk) bb[c][kk] = *(const f16x8*)(p + kk * 32);
    }
    float bnv[4];
#pragma unroll
    for (int c = 0; c < 4; ++c) bnv[c] = bnn[(dgr * 4 + c) * 64 + fw * 16 + l15];

#pragma unroll
    for (int m = 0; m < 4; ++m) {
      const int arow = (eh * 64 + m * 16 + l15) * 128 + aoff;
      f32x4 C[4];
#pragma unroll
      for (int c = 0; c < 4; ++c)
        C[c] = (f32x4){bnv[c], bnv[c], bnv[c], bnv[c]};   // bias pre-loaded
#pragma unroll
      for (int kk = 0; kk < 4; ++kk) {
        int kgp = (kk * 4 + q) ^ l15;   // e&15 == l15 for this wave's A rows
        f16x8 a = *(const f16x8*)&Ae[arow + kgp * 8];
#pragma unroll
        for (int c = 0; c < 4; ++c)
          C[c] = __builtin_amdgcn_mfma_f32_16x16x32_f16(a, bb[c][kk], C[c], 0, 0, 0);
      }
#pragma unroll
      for (int c = 0; c < 4; ++c) {
        int d = dgr * 4 + c;
        float4 hv = *(const float4*)&Hs[d * 132 + eh * 64 + m * 16 + q * 4];
        msg[m][0] = fmaf(hv.x, fmaxf(C[c][0], 0.f), msg[m][0]);
        msg[m][1] = fmaf(hv.y, fmaxf(C[c][1], 0.f), msg[m][1]);
        msg[m][2] = fmaf(hv.z, fmaxf(C[c][2], 0.f), msg[m][2]);
        msg[m][3] = fmaf(hv.w, fmaxf(C[c][3], 0.f), msg[m][3]);
      }
    }
  }

  // plain fp16 stores (no atomics) -> msgbuf[e][f]
#pragma unroll
  for (int m = 0; m < 4; ++m)
#pragma unroll
    for (int rr = 0; rr < 4; ++rr) {
      int e = ebase + eh * 64 + m * 16 + q * 4 + rr;
      msgbuf[(size_t)e * 64 + fw * 16 + l15] = (_Float16)msg[m][rr];
    }
}

// ---------------------------------------------------------------------------
// node_update_g: agg via CSR gather of msgbuf; m = relu(agg + h@W_root+b);
// GRU gates gate-column-per-thread (weights read once per block); h (f32,
// d_out) updated in place. Block = 16 nodes, 256 threads.
// ---------------------------------------------------------------------------
__launch_bounds__(256)
__global__ void node_update_g(const _Float16* __restrict__ msgbuf,
                              const int* __restrict__ rowptr,
                              const int* __restrict__ eids,
                              float* __restrict__ hid,
                              const float* __restrict__ Wroot,
                              const float* __restrict__ bconv,
                              const float* __restrict__ wih,
                              const float* __restrict__ whh,
                              const float* __restrict__ bih,
                              const float* __restrict__ bhh) {
  __shared__ __align__(16) float shT[64 * 20];   // h^T  [k][nl], stride 20
  __shared__ __align__(16) float smT[64 * 20];   // m^T  [k][nl]
  __shared__ __align__(16) float sg[16 * 384];   // gates
  __shared__ __align__(16) float sW[64 * 64];    // Wroot
  const int t = threadIdx.x;
  const int nb = blockIdx.x * 16;

  // stage Wroot (f32, 16KB)
#pragma unroll
  for (int i = 0; i < 4; ++i) {
    int g = i * 256 + t;
    *(float4*)&sW[g * 4] = *(const float4*)&Wroot[g * 4];
  }
  // stage h transposed
#pragma unroll
  for (int i = 0; i < 4; ++i) {
    int idx = i * 256 + t;
    int nl = idx >> 6, dc = idx & 63;
    shT[dc * 20 + nl] = hid[(size_t)(nb + nl) * 64 + dc];
  }
  __syncthreads();

  // phase 1: gather msg + root matmul -> m (write transposed)
#pragma unroll
  for (int i = 0; i < 4; ++i) {
    int idx = i * 256 + t;
    int nl = idx >> 6, dc = idx & 63;
    int n = nb + nl;
    float acc = bconv[dc];
    int r0 = rowptr[n], r1 = rowptr[n + 1];
    for (int j = r0; j < r1; ++j)
      acc += (float)msgbuf[(size_t)eids[j] * 64 + dc];
    for (int k = 0; k < 64; ++k)
      acc = fmaf(shT[k * 20 + nl], sW[k * 64 + dc], acc);
    smT[dc * 20 + nl] = fmaxf(acc, 0.f);
  }
  __syncthreads();

  // phase 2: gates — thread owns one gate column, accumulates 16 nodes in regs
  for (int p = 0; p < 2; ++p) {
    int j2 = p * 256 + t;
    if (j2 < 384) {
      bool is_ih = (j2 < 192);
      int col = is_ih ? j2 : j2 - 192;
      const float* W = is_ih ? wih : whh;
      float bias = is_ih ? bih[col] : bhh[col];
      const float* inT = is_ih ? smT : shT;
      float a[16];
#pragma unroll
      for (int nl = 0; nl < 16; ++nl) a[nl] = bias;
      for (int k = 0; k < 64; ++k) {
        float wv = W[k * 192 + col];
        float4 v0 = *(const float4*)&inT[k * 20 + 0];
        float4 v1 = *(const float4*)&inT[k * 20 + 4];
        float4 v2 = *(const float4*)&inT[k * 20 + 8];
        float4 v3 = *(const float4*)&inT[k * 20 + 12];
        a[0]  = fmaf(v0.x, wv, a[0]);  a[1]  = fmaf(v0.y, wv, a[1]);
        a[2]  = fmaf(v0.z, wv, a[2]);  a[3]  = fmaf(v0.w, wv, a[3]);
        a[4]  = fmaf(v1.x, wv, a[4]);  a[5]  = fmaf(v1.y, wv, a[5]);
        a[6]  = fmaf(v1.z, wv, a[6]);  a[7]  = fmaf(v1.w, wv, a[7]);
        a[8]  = fmaf(v2.x, wv, a[8]);  a[9]  = fmaf(v2.y, wv, a[9]);
        a[10] = fmaf(v2.z, wv, a[10]); a[11] = fmaf(v2.w, wv, a[11]);
        a[12] = fmaf(v3.x, wv, a[12]); a[13] = fmaf(v3.y, wv, a[13]);
        a[14] = fmaf(v3.z, wv, a[14]); a[15] = fmaf(v3.w, wv, a[15]);
      }
#pragma unroll
      for (int nl = 0; nl < 16; ++nl) sg[nl * 384 + j2] = a[nl];
    }
  }
  __syncthreads();

  // phase 3: GRU elementwise
#pragma unroll
  for (int i = 0; i < 4; ++i) {
    int idx = i * 256 + t;
    int nl = idx >> 6, dc = idx & 63;
    const float* g = &sg[nl * 384];
    float ir = g[dc], iz = g[64 + dc], in_ = g[128 + dc];
    float hr = g[192 + dc], hz = g[256 + dc], hn = g[320 + dc];
    float r = sigm(ir + hr), z = sigm(iz + hz);
    float nc = tanhf(in_ + r * hn);
    hid[(size_t)nb * 64 + idx] = (1.f - z) * nc + z * shT[dc * 20 + nl];
  }
}

// ---------------------------------------------------------------------------
// edge_mlp (MFMA, fp16, v2): e' = relu(relu([h[row]|h[col]|e]@We1+b1)@We2+b2)
// 64 edges/block, 4 waves. R19 change: ALL 24 B fragments (We1T 16, We2T 8)
// hoisted to registers BEFORE the As staging loop — their ~200-300cy global
// latency hides under staging + barrier instead of stalling the MFMA loops
// (same exposed-latency pattern measured in fused_msg). 4-wave block +
// launch_bounds(256,1) grants the 256-VGPR budget (empirical: only (<=256,1)
// does); natural demand ~190, no spill expected.
// ---------------------------------------------------------------------------
__launch_bounds__(256, 1)
__global__ void edge_mlp_m(const float* __restrict__ hid,
                           float* __restrict__ ebf,
                           const int* __restrict__ eidx,
                           const _Float16* __restrict__ We1T,
                           const float* __restrict__ be1,
                           const _Float16* __restrict__ We2T,
                           const float* __restrict__ be2) {
  __shared__ _Float16 As[64 * 264];   // 33,792 B
  __shared__ _Float16 Ts[64 * 136];   // 17,408 B
  const int t = threadIdx.x;
  const int w = t >> 6, l = t & 63, l15 = l & 15, q = l >> 4;
  const int mbase = blockIdx.x * 64;

  // ---- hoisted B fragments: issue all 24 global loads up front ----
  f16x8 B1[4][2][2];   // [kc][kk][nn]
#pragma unroll
  for (int kc = 0; kc < 4; ++kc)
#pragma unroll
    for (int kk = 0; kk < 2; ++kk) {
      int ko = kc * 64 + kk * 32 + q * 8;
      B1[kc][kk][0] = *(const f16x8*)(We1T + (size_t)(w * 32 + l15) * 256 + ko);
      B1[kc][kk][1] = *(const f16x8*)(We1T + (size_t)(w * 32 + 16 + l15) * 256 + ko);
    }
  f16x8 B2[2][2][2];   // [kc][kk][nn]
#pragma unroll
  for (int kc = 0; kc < 2; ++kc)
#pragma unroll
    for (int kk = 0; kk < 2; ++kk) {
      int ko = kc * 64 + kk * 32 + q * 8;
      B2[kc][kk][0] = *(const f16x8*)(We2T + (size_t)(w * 32 + l15) * 128 + ko);
      B2[kc][kk][1] = *(const f16x8*)(We2T + (size_t)(w * 32 + 16 + l15) * 128 + ko);
    }
  float bv1_0 = be1[w * 32 + l15],      bv1_1 = be1[w * 32 + 16 + l15];
  float bv2_0 = be2[w * 32 + l15],      bv2_1 = be2[w * 32 + 16 + l15];

  // ---- As staging (B loads complete under this + the barrier) ----
  for (int g = t; g < 2048; g += 256) {
    int r = g >> 5, kg = g & 31;
    int e = mbase + r;
    const float* src;
    if (kg < 8)       src = &hid[(size_t)eidx[e] * 64 + kg * 8];
    else if (kg < 16) src = &hid[(size_t)eidx[N_EDGES + e] * 64 + (kg - 8) * 8];
    else              src = &ebf[(size_t)e * 128 + (kg - 16) * 8];
    *(f16x8*)&As[r * 264 + kg * 8] = packh8(src);
  }
  __syncthreads();

  f32x4 zero4 = {0.f, 0.f, 0.f, 0.f};
  f32x4 acc[4][2];
#pragma unroll
  for (int m = 0; m < 4; ++m)
#pragma unroll
    for (int nn = 0; nn < 2; ++nn) acc[m][nn] = zero4;

#pragma unroll
  for (int kc = 0; kc < 4; ++kc)
#pragma unroll
    for (int kk = 0; kk < 2; ++kk) {
      int ko = kc * 64 + kk * 32 + q * 8;
#pragma unroll
      for (int m = 0; m < 4; ++m) {
        f16x8 a = *(const f16x8*)&As[(m * 16 + l15) * 264 + ko];
        acc[m][0] = __builtin_amdgcn_mfma_f32_16x16x32_f16(a, B1[kc][kk][0], acc[m][0], 0, 0, 0);
        acc[m][1] = __builtin_amdgcn_mfma_f32_16x16x32_f16(a, B1[kc][kk][1], acc[m][1], 0, 0, 0);
      }
    }

#pragma unroll
  for (int m = 0; m < 4; ++m)
#pragma unroll
    for (int nn = 0; nn < 2; ++nn) {
      int col = w * 32 + nn * 16 + l15;
      float bv = nn ? bv1_1 : bv1_0;
#pragma unroll
      for (int rr = 0; rr < 4; ++rr) {
        int row = m * 16 + q * 4 + rr;
        Ts[row * 136 + col] = (_Float16)fmaxf(acc[m][nn][rr] + bv, 0.f);
      }
    }
  __syncthreads();

  f32x4 acc2[4][2];
#pragma unroll
  for (int m = 0; m < 4; ++m)
#pragma unroll
    for (int nn = 0; nn < 2; ++nn) acc2[m][nn] = zero4;

#pragma unroll
  for (int kc = 0; kc < 2; ++kc)
#pragma unroll
    for (int kk = 0; kk < 2; ++kk) {
      int ko = kc * 64 + kk * 32 + q * 8;
#pragma unroll
      for (int m = 0; m < 4; ++m) {
        f16x8 a = *(const f16x8*)&Ts[(m * 16 + l15) * 136 + ko];
        acc2[m][0] = __builtin_amdgcn_mfma_f32_16x16x32_f16(a, B2[kc][kk][0], acc2[m][0], 0, 0, 0);
        acc2[m][1] = __builtin_amdgcn_mfma_f32_16x16x32_f16(a, B2[kc][kk][1], acc2[m][1], 0, 0, 0);
      }
    }

#pragma unroll
  for (int m = 0; m < 4; ++m)
#pragma unroll
    for (int nn = 0; nn < 2; ++nn) {
      int col = w * 32 + nn * 16 + l15;
      float bv = nn ? bv2_1 : bv2_0;
#pragma unroll
      for (int rr = 0; rr < 4; ++rr) {
        int row = mbase + m * 16 + q * 4 + rr;
        ebf[(size_t)row * 128 + col] = fmaxf(acc2[m][nn][rr] + bv, 0.f);
      }
    }
}

// ---------------------------------------------------------------------------
extern "C" void kernel_launch(void* const* d_in, const int* in_sizes, int n_in,
                              void* d_out, int out_size, void* d_ws, size_t ws_size,
                              hipStream_t stream) {
  const float* nf    = (const float*)d_in[0];
  const float* ea    = (const float*)d_in[1];
  const int*   eidx  = (const int*)d_in[2];
  const float* Wp    = (const float*)d_in[3];
  const float* bp    = (const float*)d_in[4];
  const float* Wpe   = (const float*)d_in[5];
  const float* bpe   = (const float*)d_in[6];
  const float* Wnn   = (const float*)d_in[7];
  const float* bnn   = (const float*)d_in[8];
  const float* Wroot = (const float*)d_in[9];
  const float* bconv = (const float*)d_in[10];
  const float* wih   = (const float*)d_in[11];
  const float* whh   = (const float*)d_in[12];
  const float* bih   = (const float*)d_in[13];
  const float* bhh   = (const float*)d_in[14];
  const float* We1   = (const float*)d_in[15];
  const float* be1   = (const float*)d_in[16];
  const float* We2   = (const float*)d_in[17];
  const float* be2   = (const float*)d_in[18];

  // h and e live in d_out (f32 masters), fully rewritten every launch.
  float* hid = (float*)d_out;                 // 4096*64
  float* ebf = (float*)d_out + 4096 * 64;     // 32768*128

  // workspace: 5,505,152 B
  char* ws = (char*)d_ws;
  _Float16* WnnT   = (_Float16*)(ws + 0);          // 1,048,576
  _Float16* We1T   = (_Float16*)(ws + 1048576);    //    65,536
  _Float16* We2T   = (_Float16*)(ws + 1114112);    //    32,768
  _Float16* msgbuf = (_Float16*)(ws + 1146880);    // 4,194,304
  int*      rowptr = (int*)(ws + 5341184);         //    16,512 (4097 used)
  int*      cursor = (int*)(ws + 5357696);         //    16,384
  int*      eids   = (int*)(ws + 5374080);         //   131,072

  prep_all<<<320, 256, 0, stream>>>(Wnn, We1, We2, WnnT, We1T, We2T);
  // blocks 0..15: zero cursor (as rowcnt); 16..1039: proj_node
  zero_projnode<<<1040, 256, 0, stream>>>(nf, Wp, bp, hid, cursor);
  // blocks 0..127: csr_count into cursor; 128..1151: proj_edge
  count_projedge<<<1152, 256, 0, stream>>>(ea, Wpe, bpe, ebf, eidx, cursor);
  csr_scan<<<1, 1024, 0, stream>>>(cursor, rowptr, cursor);
  csr_fill<<<128, 256, 0, stream>>>(eidx, cursor, eids);

  for (int s = 0; s < 3; ++s) {
    fused_msg_m<<<256, 512, 0, stream>>>(ebf, hid, WnnT, bnn, eidx, msgbuf);
    node_update_g<<<256, 256, 0, stream>>>(msgbuf, rowptr, eids, hid, Wroot, bconv,
                                           wih, whh, bih, bhh);
    edge_mlp_m<<<512, 256, 0, stream>>>(hid, ebf, eidx, We1T, be1, We2T, be2);
  }
}